// Round 3
// baseline (104.910 us; speedup 1.0000x reference)
//
#include <hip/hip_runtime.h>
#include <hip/hip_bf16.h>

// EfficientSelfAttn (PVT spatial-reduction attention), fp32 in/out.
// B=8, N=16384, C=64, NH=1, SR=8, H=W=128 -> Nk=256.
//
// R3: k2 with in-register P fragments (shfl half-exchange), f32 LDS O-reduce,
// XOR-swizzled LDS (<=2-way), hoisted K/V/W fragment loads, setprio. k1 at
// 512 blocks (4 patches each).

namespace {

constexpr int kN = 16384;

// ---- ws byte layout ----
constexpr size_t OFF_WSRT = 0;              // f32 [r=kh*8+kw][ic][oc] 64*64*64
constexpr size_t OFF_WKVT = 1048576;        // f32 [c][j] 64*128
constexpr size_t OFF_WQF  = 1081344;        // bf16 frag [pl2][ks4][ct2][64][8]
constexpr size_t OFF_WPF  = 1097728;        // bf16 frag [pl2][ks4][ct2][64][8]
constexpr size_t OFF_KF   = 1114112;        // bf16 frag [b][pl2][tr8][ks4][64][8]
constexpr size_t OFF_VF   = 1638400;        // bf16 frag [b][pl2][ks16][ct2][64][8]

typedef __attribute__((ext_vector_type(8))) __bf16 bhalf8;
typedef __attribute__((ext_vector_type(16))) float f32x16;

#define MFMA32(a, b, c) __builtin_amdgcn_mfma_f32_32x32x16_bf16((a), (b), (c), 0, 0, 0)

__device__ __forceinline__ void split1(float x, unsigned short& h, unsigned short& l) {
  unsigned u = __float_as_uint(x);
  h = (unsigned short)(u >> 16);
  float r = x - __uint_as_float(u & 0xFFFF0000u);
  l = (unsigned short)(__float_as_uint(r) >> 16);
}

// pack two f32 into one dword of bf16-hi parts; lo parts via out param
__device__ __forceinline__ unsigned pack2(float a, float b, unsigned& lo) {
  unsigned ua = __float_as_uint(a), ub = __float_as_uint(b);
  unsigned hi = (ua >> 16) | (ub & 0xFFFF0000u);
  float ra = a - __uint_as_float(ua & 0xFFFF0000u);
  float rb = b - __uint_as_float(ub & 0xFFFF0000u);
  lo = (__float_as_uint(ra) >> 16) | (__float_as_uint(rb) & 0xFFFF0000u);
  return hi;
}

union U4 { unsigned u[4]; bhalf8 v; };
union U8F { float f[8]; struct { float4 a, b; } q; };

// assemble an MFMA A/B fragment (8 bf16 = keys lh*8..lh*8+7 of a 16-slice)
// from 4 packed dwords P[0..3] = pairs (r0,r1)(r2,r3)(r4,r5)(r6,r7) of the
// 32x32 C-layout rows; cross-half data fetched via shfl_xor(32).
__device__ __forceinline__ bhalf8 asm_frag(const unsigned* P, int lh) {
  unsigned o0 = __shfl_xor(P[0], 32);
  unsigned o1 = __shfl_xor(P[1], 32);
  unsigned o2 = __shfl_xor(P[2], 32);
  unsigned o3 = __shfl_xor(P[3], 32);
  U4 r;
  r.u[0] = lh ? o2 : P[0];
  r.u[1] = lh ? o3 : P[1];
  r.u[2] = lh ? P[2] : o0;
  r.u[3] = lh ? P[3] : o1;
  return r.v;
}

__device__ __forceinline__ void split8(const float* xs, bhalf8& h8, bhalf8& l8) {
  U4 H, L;
#pragma unroll
  for (int p = 0; p < 4; ++p) H.u[p] = pack2(xs[2 * p], xs[2 * p + 1], L.u[p]);
  h8 = H.v;
  l8 = L.v;
}

// ---- k0: weight reorder + fragment/split generation ------------------------
__global__ __launch_bounds__(256) void k0_reorder(
    const float* __restrict__ wq, const float* __restrict__ wkv,
    const float* __restrict__ wproj, const float* __restrict__ wsr,
    char* __restrict__ wsb) {
  int e = blockIdx.x * 256 + threadIdx.x;
  if (e < 262144) {
    int oc = e & 63, ic = (e >> 6) & 63, r = e >> 12;
    ((float*)(wsb + OFF_WSRT))[e] = wsr[oc * 4096 + ic * 64 + r];
  } else if (e < 270336) {
    int i = e - 262144;
    int j = i & 127, c = i >> 7;
    ((float*)(wsb + OFF_WKVT))[i] = wkv[j * 64 + c];
  } else if (e < 278528) {
    int i = e - 270336;
    bool iswp = i >= 4096;
    int ii = i & 4095;
    int e8 = ii & 7, ln = (ii >> 3) & 63, ct = (ii >> 9) & 1, ks = ii >> 10;
    int cc = ct * 32 + (ln & 31);
    int kk = ks * 16 + (ln >> 5) * 8 + e8;
    const float* src = iswp ? wproj : wq;
    float v = src[cc * 64 + kk];
    unsigned short h, l;
    split1(v, h, l);
    size_t base = (iswp ? OFF_WPF : OFF_WQF) + (size_t)ii * 2;
    *(unsigned short*)(wsb + base) = h;
    *(unsigned short*)(wsb + base + 8192) = l;
  }
}

// ---- k1: conv + LN + KV, emits K/V hi+lo fragments -------------------------
// grid: 512 = 8 batches * 64 patch-groups (4 patches each). 256 threads.
__global__ __launch_bounds__(256) void k1_conv_ln_kv(
    const float* __restrict__ x, const float* __restrict__ bkv,
    const float* __restrict__ gamma, const float* __restrict__ beta,
    char* __restrict__ wsb) {
  const float* __restrict__ wsrT = (const float*)(wsb + OFF_WSRT);
  const float* __restrict__ wkvT = (const float*)(wsb + OFF_WKVT);

  const int b  = blockIdx.x >> 6;
  const int pg = blockIdx.x & 63;
  const int t  = threadIdx.x;
  const int ocp = t & 31;
  const int icg = t >> 5;

  __shared__ float chunk[2048];  // [p4][kw8][ic64] for one kh slab
  __shared__ float red[2048];    // [icg8][oc*4+p]
  __shared__ float cvout[256];   // [p][oc]
  __shared__ float xnl[256];     // [p][oc]

  const float* __restrict__ xb = x + (size_t)b * (kN * 64);

  float acc0[4], acc1[4];
#pragma unroll
  for (int p = 0; p < 4; ++p) { acc0[p] = 0.f; acc1[p] = 0.f; }

  for (int kh = 0; kh < 8; ++kh) {
    __syncthreads();
#pragma unroll
    for (int it = 0; it < 2; ++it) {
      int f = it * 1024 + t * 4;
      int p = f >> 9;
      int w512 = f & 511;
      int pid = pg * 4 + p;
      int oh = pid >> 4, ow = pid & 15;
      const float* src = xb + oh * 65536 + ow * 512 + kh * 8192 + w512;
      *(float4*)&chunk[f] = *(const float4*)src;
    }
    __syncthreads();
    for (int kw = 0; kw < 8; ++kw) {
      const int rbase = ((kh * 8 + kw) * 64 + icg * 8) * 64;
      float w0[8], w1[8];
#pragma unroll
      for (int ii = 0; ii < 8; ++ii) {
        w0[ii] = wsrT[rbase + ii * 64 + ocp];
        w1[ii] = wsrT[rbase + ii * 64 + ocp + 32];
      }
#pragma unroll
      for (int p = 0; p < 4; ++p) {
        const float* cp = &chunk[p * 512 + kw * 64 + icg * 8];
        float4 a = *(const float4*)cp;
        float4 bb = *(const float4*)(cp + 4);
        float xs[8] = {a.x, a.y, a.z, a.w, bb.x, bb.y, bb.z, bb.w};
#pragma unroll
        for (int ii = 0; ii < 8; ++ii) {
          acc0[p] = fmaf(w0[ii], xs[ii], acc0[p]);
          acc1[p] = fmaf(w1[ii], xs[ii], acc1[p]);
        }
      }
    }
  }

#pragma unroll
  for (int p = 0; p < 4; ++p) {
    red[icg * 256 + ocp * 4 + p] = acc0[p];
    red[icg * 256 + (ocp + 32) * 4 + p] = acc1[p];
  }
  __syncthreads();
  {
    int e = t;  // e = oc*4 + p
    float s = 0.f;
#pragma unroll
    for (int g = 0; g < 8; ++g) s += red[g * 256 + e];
    cvout[(e & 3) * 64 + (e >> 2)] = s;
  }
  __syncthreads();

  const int lane = t & 63;
  const int wid = t >> 6;
  {
    int p = wid;
    float val = cvout[p * 64 + lane];
    float ssum = val;
#pragma unroll
    for (int off = 1; off < 64; off <<= 1) ssum += __shfl_xor(ssum, off);
    float mean = ssum * (1.f / 64.f);
    float dv = val - mean;
    float sq = dv * dv;
#pragma unroll
    for (int off = 1; off < 64; off <<= 1) sq += __shfl_xor(sq, off);
    float rs = 1.0f / sqrtf(sq * (1.f / 64.f) + 1e-5f);
    xnl[p * 64 + lane] = dv * rs * gamma[lane] + beta[lane];
  }
  __syncthreads();

  // KV projection: pgk = t>>7 (2 patches each), j = t&127
  const int pgk = t >> 7;
  const int j = t & 127;
  float a2[2] = {0.f, 0.f};
  for (int c = 0; c < 64; ++c) {
    float w = wkvT[c * 128 + j];
#pragma unroll
    for (int q = 0; q < 2; ++q)
      a2[q] = fmaf(xnl[(pgk * 2 + q) * 64 + c], w, a2[q]);
  }
  float bj = bkv[j];
#pragma unroll
  for (int q = 0; q < 2; ++q) {
    int p = pgk * 2 + q;
    int pid = pg * 4 + p;  // key index
    float val = a2[q] + bj;
    unsigned short h, l;
    split1(val, h, l);
    if (j < 64) {
      int tr = pid >> 5, ks = j >> 4, e8 = j & 7;
      int ln = (pid & 31) | (((j >> 3) & 1) << 5);
      size_t base = OFF_KF + (size_t)(b * 2) * 32768 +
                    (size_t)((tr * 4 + ks) * 64 + ln) * 16 + e8 * 2;
      *(unsigned short*)(wsb + base) = h;
      *(unsigned short*)(wsb + base + 32768) = l;
    } else {
      int d = j - 64;
      int ct = d >> 5, ks = pid >> 4, e8 = pid & 7;
      int ln = (d & 31) | (((pid >> 3) & 1) << 5);
      size_t base = OFF_VF + (size_t)(b * 2) * 32768 +
                    (size_t)((ks * 2 + ct) * 64 + ln) * 16 + e8 * 2;
      *(unsigned short*)(wsb + base) = h;
      *(unsigned short*)(wsb + base + 32768) = l;
    }
  }
}

// ---- k2: MFMA attention ----------------------------------------------------
// grid: 2048 = 8 batches * 256 row-blocks (64 queries each). 4 waves.
// LDS 34 KB: [0,16K)=Q rows (256B, XOR q&15) aliased later as Of0 f32;
// [16K,32K)=Of1; [32K,+2K)=SMP.
__global__ __launch_bounds__(256) void k2_attn(
    const float* __restrict__ x, const float* __restrict__ bq,
    const float* __restrict__ bproj, const char* __restrict__ wsb,
    float* __restrict__ out) {
  const int b  = blockIdx.x >> 8;
  const int rb = blockIdx.x & 255;
  const int n0 = rb * 64;
  const int t = threadIdx.x;
  const int w = t >> 6;
  const int lane = t & 63;
  const int l31 = lane & 31;
  const int lh = lane >> 5;
  const int qt = w >> 1, ct = w & 1;

  __shared__ __align__(16) char sm[34816];
  char* QO = sm;
  float2* SMP = (float2*)(sm + 32768);

  const char* kf_b = wsb + OFF_KF + (size_t)(b * 2) * 32768;
  const char* vf_b = wsb + OFF_VF + (size_t)(b * 2) * 32768;

  // ---- hoisted K A-fragment loads (consumed in QK, latency hidden by q-proj)
  bhalf8 KAh[2][4], KAl[2][4];
#pragma unroll
  for (int i = 0; i < 2; ++i)
#pragma unroll
    for (int ks = 0; ks < 4; ++ks) {
      const char* p = kf_b + (size_t)(((w * 2 + i) * 4 + ks) * 64 + lane) * 16;
      KAh[i][ks] = *(const bhalf8*)p;
      KAl[i][ks] = *(const bhalf8*)(p + 32768);
    }

  // ---- q-proj: Q = X @ Wq^T (+bq)*0.125 ; X A-frags straight from global ---
  {
    const float* xrow = x + ((size_t)b * kN + n0 + qt * 32 + l31) * 64 + lh * 8;
    float4 X0[4], X1[4];
#pragma unroll
    for (int ks = 0; ks < 4; ++ks) {
      X0[ks] = *(const float4*)(xrow + ks * 16);
      X1[ks] = *(const float4*)(xrow + ks * 16 + 4);
    }
    bhalf8 Wh[4], Wl[4];
#pragma unroll
    for (int ks = 0; ks < 4; ++ks) {
      const char* p = wsb + OFF_WQF + (size_t)((ks * 2 + ct) * 64 + lane) * 16;
      Wh[ks] = *(const bhalf8*)p;
      Wl[ks] = *(const bhalf8*)(p + 8192);
    }
    f32x16 acc;
#pragma unroll
    for (int r = 0; r < 16; ++r) acc[r] = 0.f;
#pragma unroll
    for (int ks = 0; ks < 4; ++ks) {
      U8F u;
      u.q.a = X0[ks]; u.q.b = X1[ks];
      bhalf8 ah, al;
      split8(u.f, ah, al);
      acc = MFMA32(ah, Wh[ks], acc);
      acc = MFMA32(ah, Wl[ks], acc);
      acc = MFMA32(al, Wh[ks], acc);
    }
    const int c = ct * 32 + l31;
    const float bias = bq[c];
#pragma unroll
    for (int r = 0; r < 16; ++r) {
      int q = qt * 32 + (r & 3) + 8 * (r >> 2) + 4 * lh;
      float v = (acc[r] + bias) * 0.125f;
      unsigned short h, l;
      split1(v, h, l);
      char* row = QO + q * 256;
      int sw = (q & 15) << 4;
      *(unsigned short*)(row + ((c * 2) ^ sw)) = h;
      *(unsigned short*)(row + ((128 + c * 2) ^ sw)) = l;
    }
  }
  __syncthreads();  // (1) Q visible

  // ---- QK: S^T = K @ Q^T ; wave w -> keys 64w..64w+63, cols = all 64 q -----
  f32x16 accS[2][2];
#pragma unroll
  for (int i = 0; i < 2; ++i)
#pragma unroll
    for (int j = 0; j < 2; ++j)
#pragma unroll
      for (int r = 0; r < 16; ++r) accS[i][j][r] = 0.f;

  __builtin_amdgcn_s_setprio(1);
#pragma unroll
  for (int j = 0; j < 2; ++j) {
    const int qq = j * 32 + l31;
    const char* qr = QO + qq * 256;
    const int swq = (qq & 15) << 4;
#pragma unroll
    for (int ks = 0; ks < 4; ++ks) {
      bhalf8 bh = *(const bhalf8*)(qr + ((ks * 32 + lh * 16) ^ swq));
      bhalf8 bl = *(const bhalf8*)(qr + ((128 + ks * 32 + lh * 16) ^ swq));
#pragma unroll
      for (int i = 0; i < 2; ++i) {
        accS[i][j] = MFMA32(KAh[i][ks], bh, accS[i][j]);
        accS[i][j] = MFMA32(KAh[i][ks], bl, accS[i][j]);
        accS[i][j] = MFMA32(KAl[i][ks], bh, accS[i][j]);
      }
    }
  }
  __builtin_amdgcn_s_setprio(0);

  // ---- softmax: wave-local partials, cross-wave combine via SMP ------------
  float mloc[2];
#pragma unroll
  for (int j = 0; j < 2; ++j) {
    float m = -1e30f;
#pragma unroll
    for (int i = 0; i < 2; ++i)
#pragma unroll
      for (int r = 0; r < 16; ++r) m = fmaxf(m, accS[i][j][r]);
    m = fmaxf(m, __shfl_xor(m, 32));
    float s = 0.f;
#pragma unroll
    for (int i = 0; i < 2; ++i)
#pragma unroll
      for (int r = 0; r < 16; ++r) {
        float e = __expf(accS[i][j][r] - m);
        accS[i][j][r] = e;
        s += e;
      }
    s += __shfl_xor(s, 32);
    mloc[j] = m;
    if (lh == 0) SMP[w * 64 + j * 32 + l31] = make_float2(m, s);
  }
  __syncthreads();  // (2) SMP visible; all Q reads complete

  float fj[2];
#pragma unroll
  for (int j = 0; j < 2; ++j) {
    float2 p0 = SMP[0 * 64 + j * 32 + l31];
    float2 p1 = SMP[1 * 64 + j * 32 + l31];
    float2 p2 = SMP[2 * 64 + j * 32 + l31];
    float2 p3 = SMP[3 * 64 + j * 32 + l31];
    float M = fmaxf(fmaxf(p0.x, p1.x), fmaxf(p2.x, p3.x));
    float T = p0.y * __expf(p0.x - M) + p1.y * __expf(p1.x - M) +
              p2.y * __expf(p2.x - M) + p3.y * __expf(p3.x - M);
    fj[j] = __expf(mloc[j] - M) / T;
  }

  // pack P to bf16 hi/lo pairs (kills accS)
  unsigned HPK[2][2][8], LPK[2][2][8];
#pragma unroll
  for (int i = 0; i < 2; ++i)
#pragma unroll
    for (int j = 0; j < 2; ++j)
#pragma unroll
      for (int pr = 0; pr < 8; ++pr)
        HPK[i][j][pr] = pack2(accS[i][j][2 * pr] * fj[j],
                              accS[i][j][2 * pr + 1] * fj[j], LPK[i][j][pr]);

  // ---- PV: per-wave partial O over own 64 keys; P frags assembled in-reg ---
  f32x16 accO[2][2];  // [q-tile j][d-tile c2]
#pragma unroll
  for (int j = 0; j < 2; ++j)
#pragma unroll
    for (int c2 = 0; c2 < 2; ++c2)
#pragma unroll
      for (int r = 0; r < 16; ++r) accO[j][c2][r] = 0.f;

  __builtin_amdgcn_s_setprio(1);
#pragma unroll
  for (int i = 0; i < 2; ++i) {
    bhalf8 Vh[2][2], Vl[2][2];  // [s][c2]
#pragma unroll
    for (int s = 0; s < 2; ++s)
#pragma unroll
      for (int c2 = 0; c2 < 2; ++c2) {
        const char* p =
            vf_b + (size_t)(((w * 4 + i * 2 + s) * 2 + c2) * 64 + lane) * 16;
        Vh[s][c2] = *(const bhalf8*)p;
        Vl[s][c2] = *(const bhalf8*)(p + 32768);
      }
#pragma unroll
    for (int j = 0; j < 2; ++j)
#pragma unroll
      for (int s = 0; s < 2; ++s) {
        bhalf8 fh = asm_frag(&HPK[i][j][s * 4], lh);
        bhalf8 fl = asm_frag(&LPK[i][j][s * 4], lh);
#pragma unroll
        for (int c2 = 0; c2 < 2; ++c2) {
          accO[j][c2] = MFMA32(fh, Vh[s][c2], accO[j][c2]);
          accO[j][c2] = MFMA32(fh, Vl[s][c2], accO[j][c2]);
          accO[j][c2] = MFMA32(fl, Vh[s][c2], accO[j][c2]);
        }
      }
  }
  __builtin_amdgcn_s_setprio(0);

  // ---- O reduce through f32 LDS (two regions, 16B-slot XOR swizzle) --------
  // byte addr = q*256 + ((d*4) ^ ((q&15)<<4))
  if (w < 2) {
    char* Of = sm + (w == 1 ? 16384 : 0);
#pragma unroll
    for (int j = 0; j < 2; ++j)
#pragma unroll
      for (int c2 = 0; c2 < 2; ++c2)
#pragma unroll
        for (int r = 0; r < 16; ++r) {
          int q = j * 32 + (r & 3) + 8 * (r >> 2) + 4 * lh;
          int d = c2 * 32 + l31;
          *(float*)(Of + q * 256 + ((d * 4) ^ ((q & 15) << 4))) = accO[j][c2][r];
        }
  }
  __syncthreads();  // (3)

  // hoist Wp fragment loads (consumed after barrier 4)
  bhalf8 WpH[4], WpL[4];
#pragma unroll
  for (int ks = 0; ks < 4; ++ks) {
    const char* p = wsb + OFF_WPF + (size_t)((ks * 2 + ct) * 64 + lane) * 16;
    WpH[ks] = *(const bhalf8*)p;
    WpL[ks] = *(const bhalf8*)(p + 8192);
  }

  if (w >= 2) {
    char* Of = sm + (w == 3 ? 16384 : 0);
#pragma unroll
    for (int j = 0; j < 2; ++j)
#pragma unroll
      for (int c2 = 0; c2 < 2; ++c2)
#pragma unroll
        for (int r = 0; r < 16; ++r) {
          int q = j * 32 + (r & 3) + 8 * (r >> 2) + 4 * lh;
          int d = c2 * 32 + l31;
          float* a = (float*)(Of + q * 256 + ((d * 4) ^ ((q & 15) << 4)));
          *a += accO[j][c2][r];
        }
  }
  __syncthreads();  // (4) O complete

  // ---- out-proj: out = O @ Wp^T + bproj ------------------------------------
  {
    f32x16 acc;
#pragma unroll
    for (int r = 0; r < 16; ++r) acc[r] = 0.f;
    const int qrow = qt * 32 + l31;
    const int sw = (qrow & 15) << 4;
#pragma unroll
    for (int ks = 0; ks < 4; ++ks) {
      int base = qrow * 256;
      int off0 = (ks * 64 + lh * 32) ^ sw;
      int off1 = (ks * 64 + lh * 32 + 16) ^ sw;
      float4 a0 = *(const float4*)(sm + base + off0);
      float4 a1 = *(const float4*)(sm + base + off1);
      float4 b0 = *(const float4*)(sm + 16384 + base + off0);
      float4 b1 = *(const float4*)(sm + 16384 + base + off1);
      U8F u;
      u.f[0] = a0.x + b0.x; u.f[1] = a0.y + b0.y;
      u.f[2] = a0.z + b0.z; u.f[3] = a0.w + b0.w;
      u.f[4] = a1.x + b1.x; u.f[5] = a1.y + b1.y;
      u.f[6] = a1.z + b1.z; u.f[7] = a1.w + b1.w;
      bhalf8 ah, al;
      split8(u.f, ah, al);
      acc = MFMA32(ah, WpH[ks], acc);
      acc = MFMA32(ah, WpL[ks], acc);
      acc = MFMA32(al, WpH[ks], acc);
    }
    const int c = ct * 32 + l31;
    const float bias = bproj[c];
    float* ob = out + ((size_t)b * kN + n0) * 64;
#pragma unroll
    for (int r = 0; r < 16; ++r) {
      int q = qt * 32 + (r & 3) + 8 * (r >> 2) + 4 * lh;
      ob[q * 64 + c] = acc[r] + bias;
    }
  }
}

}  // namespace

extern "C" void kernel_launch(void* const* d_in, const int* in_sizes, int n_in,
                              void* d_out, int out_size, void* d_ws, size_t ws_size,
                              hipStream_t stream) {
  (void)in_sizes; (void)n_in; (void)out_size; (void)ws_size;
  const float* x     = (const float*)d_in[0];
  const float* wq    = (const float*)d_in[1];
  const float* bq    = (const float*)d_in[2];
  const float* wkv   = (const float*)d_in[3];
  const float* bkv   = (const float*)d_in[4];
  const float* wproj = (const float*)d_in[5];
  const float* bproj = (const float*)d_in[6];
  const float* wsr   = (const float*)d_in[7];
  const float* gamma = (const float*)d_in[8];
  const float* beta  = (const float*)d_in[9];
  float* out = (float*)d_out;
  char* wsb  = (char*)d_ws;

  k0_reorder<<<1088, 256, 0, stream>>>(wq, wkv, wproj, wsr, wsb);
  k1_conv_ln_kv<<<512, 256, 0, stream>>>(x, bkv, gamma, beta, wsb);
  k2_attn<<<2048, 256, 0, stream>>>(x, bq, bproj, wsb, out);
}

// Round 4
// 101.889 us; speedup vs baseline: 1.0297x; 1.0297x over previous
//
#include <hip/hip_runtime.h>
#include <hip/hip_bf16.h>

// EfficientSelfAttn (PVT spatial-reduction attention), fp32 in/out.
// B=8, N=16384, C=64, NH=1, SR=8, H=W=128 -> Nk=256.
//
// R4: k2 = barrier-free, LDS-free per-wave flash attention. Each wave owns 32
// queries; all GEMMs on mfma_f32_32x32x16_bf16 with 3-product hi/lo split.
// All chained operands produced transposed (queries = MFMA cols = lanes) so
// C-layout -> next B-frag is a 4-shfl half-exchange (asm_frag, validated R3).
// Online softmax with defer-max (T13); stats lane-resident, no transposes.

namespace {

constexpr int kN = 16384;

// ---- ws byte layout ----
constexpr size_t OFF_WSRT = 0;              // f32 [r=kh*8+kw][ic][oc] 64*64*64
constexpr size_t OFF_WKVT = 1048576;        // f32 [c][j] 64*128
constexpr size_t OFF_WQF  = 1081344;        // bf16 A-frag [pl2][t2][ks4][64][8]
constexpr size_t OFF_WPF  = 1097728;        // bf16 A-frag [pl2][t2][ks4][64][8]
constexpr size_t OFF_KF   = 1114112;        // bf16 A-frag [b][pl2][tr8][ks4][64][8]
constexpr size_t OFF_VF   = 1638400;        // bf16 A-frag V^T [b][pl2][td2][ks16][64][8]

typedef __attribute__((ext_vector_type(8))) __bf16 bhalf8;
typedef __attribute__((ext_vector_type(16))) float f32x16;

#define MFMA32(a, b, c) __builtin_amdgcn_mfma_f32_32x32x16_bf16((a), (b), (c), 0, 0, 0)

__device__ __forceinline__ void split1(float x, unsigned short& h, unsigned short& l) {
  unsigned u = __float_as_uint(x);
  h = (unsigned short)(u >> 16);
  float r = x - __uint_as_float(u & 0xFFFF0000u);
  l = (unsigned short)(__float_as_uint(r) >> 16);
}

// pack two f32 into one dword of bf16-hi parts; lo parts via out param
__device__ __forceinline__ unsigned pack2(float a, float b, unsigned& lo) {
  unsigned ua = __float_as_uint(a), ub = __float_as_uint(b);
  unsigned hi = (ua >> 16) | (ub & 0xFFFF0000u);
  float ra = a - __uint_as_float(ua & 0xFFFF0000u);
  float rb = b - __uint_as_float(ub & 0xFFFF0000u);
  lo = (__float_as_uint(ra) >> 16) | (__float_as_uint(rb) & 0xFFFF0000u);
  return hi;
}

union U4 { unsigned u[4]; bhalf8 v; };
union U4F { float4 v; float f[4]; };
union U8F { float f[8]; struct { float4 a, b; } q; };

// C-layout (col=lane&31, rows packed in pairs) -> A/B fragment for one
// 16-wide k-slice. P[0..3] = packed row-pairs (16s+0,1)(2,3)(8,9)(10,11)+4lh.
// Cross-half rows fetched via shfl_xor(32). Validated end-to-end in R3.
__device__ __forceinline__ bhalf8 asm_frag(const unsigned* P, int lh) {
  unsigned o0 = __shfl_xor(P[0], 32);
  unsigned o1 = __shfl_xor(P[1], 32);
  unsigned o2 = __shfl_xor(P[2], 32);
  unsigned o3 = __shfl_xor(P[3], 32);
  U4 r;
  r.u[0] = lh ? o2 : P[0];
  r.u[1] = lh ? o3 : P[1];
  r.u[2] = lh ? P[2] : o0;
  r.u[3] = lh ? P[3] : o1;
  return r.v;
}

__device__ __forceinline__ void split8(const float* xs, bhalf8& h8, bhalf8& l8) {
  U4 H, L;
#pragma unroll
  for (int p = 0; p < 4; ++p) H.u[p] = pack2(xs[2 * p], xs[2 * p + 1], L.u[p]);
  h8 = H.v;
  l8 = L.v;
}

// ---- k0: weight reorder + fragment/split generation ------------------------
__global__ __launch_bounds__(256) void k0_reorder(
    const float* __restrict__ wq, const float* __restrict__ wkv,
    const float* __restrict__ wproj, const float* __restrict__ wsr,
    char* __restrict__ wsb) {
  int e = blockIdx.x * 256 + threadIdx.x;
  if (e < 262144) {
    int oc = e & 63, ic = (e >> 6) & 63, r = e >> 12;
    ((float*)(wsb + OFF_WSRT))[e] = wsr[oc * 4096 + ic * 64 + r];
  } else if (e < 270336) {
    int i = e - 262144;
    int j = i & 127, c = i >> 7;
    ((float*)(wsb + OFF_WKVT))[i] = wkv[j * 64 + c];
  } else if (e < 278528) {
    int i = e - 270336;
    bool iswp = i >= 4096;
    int ii = i & 4095;
    // A-frag: ii = ((t2*4+ks)*64 + ln)*8 + e8 ; row c = t2*32+(ln&31),
    // k = ks*16 + (ln>>5)*8 + e8 ; value = W[c][k]
    int e8 = ii & 7, ln = (ii >> 3) & 63, ks = (ii >> 9) & 3, t2 = ii >> 11;
    int c = t2 * 32 + (ln & 31);
    int kk = ks * 16 + (ln >> 5) * 8 + e8;
    const float* src = iswp ? wproj : wq;
    float v = src[c * 64 + kk];
    unsigned short h, l;
    split1(v, h, l);
    size_t base = (iswp ? OFF_WPF : OFF_WQF) + (size_t)ii * 2;
    *(unsigned short*)(wsb + base) = h;
    *(unsigned short*)(wsb + base + 8192) = l;
  }
}

// ---- k1: conv + LN + KV, emits K and V^T hi+lo A-fragments -----------------
// grid: 512 = 8 batches * 64 patch-groups (4 patches each). 256 threads.
__global__ __launch_bounds__(256) void k1_conv_ln_kv(
    const float* __restrict__ x, const float* __restrict__ bkv,
    const float* __restrict__ gamma, const float* __restrict__ beta,
    char* __restrict__ wsb) {
  const float* __restrict__ wsrT = (const float*)(wsb + OFF_WSRT);
  const float* __restrict__ wkvT = (const float*)(wsb + OFF_WKVT);

  const int b  = blockIdx.x >> 6;
  const int pg = blockIdx.x & 63;
  const int t  = threadIdx.x;
  const int ocp = t & 31;
  const int icg = t >> 5;

  __shared__ float chunk[2048];
  __shared__ float red[2048];
  __shared__ float cvout[256];
  __shared__ float xnl[256];

  const float* __restrict__ xb = x + (size_t)b * (kN * 64);

  float acc0[4], acc1[4];
#pragma unroll
  for (int p = 0; p < 4; ++p) { acc0[p] = 0.f; acc1[p] = 0.f; }

  for (int kh = 0; kh < 8; ++kh) {
    __syncthreads();
#pragma unroll
    for (int it = 0; it < 2; ++it) {
      int f = it * 1024 + t * 4;
      int p = f >> 9;
      int w512 = f & 511;
      int pid = pg * 4 + p;
      int oh = pid >> 4, ow = pid & 15;
      const float* src = xb + oh * 65536 + ow * 512 + kh * 8192 + w512;
      *(float4*)&chunk[f] = *(const float4*)src;
    }
    __syncthreads();
    for (int kw = 0; kw < 8; ++kw) {
      const int rbase = ((kh * 8 + kw) * 64 + icg * 8) * 64;
      float w0[8], w1[8];
#pragma unroll
      for (int ii = 0; ii < 8; ++ii) {
        w0[ii] = wsrT[rbase + ii * 64 + ocp];
        w1[ii] = wsrT[rbase + ii * 64 + ocp + 32];
      }
#pragma unroll
      for (int p = 0; p < 4; ++p) {
        const float* cp = &chunk[p * 512 + kw * 64 + icg * 8];
        float4 a = *(const float4*)cp;
        float4 bb = *(const float4*)(cp + 4);
        float xs[8] = {a.x, a.y, a.z, a.w, bb.x, bb.y, bb.z, bb.w};
#pragma unroll
        for (int ii = 0; ii < 8; ++ii) {
          acc0[p] = fmaf(w0[ii], xs[ii], acc0[p]);
          acc1[p] = fmaf(w1[ii], xs[ii], acc1[p]);
        }
      }
    }
  }

#pragma unroll
  for (int p = 0; p < 4; ++p) {
    red[icg * 256 + ocp * 4 + p] = acc0[p];
    red[icg * 256 + (ocp + 32) * 4 + p] = acc1[p];
  }
  __syncthreads();
  {
    int e = t;  // e = oc*4 + p
    float s = 0.f;
#pragma unroll
    for (int g = 0; g < 8; ++g) s += red[g * 256 + e];
    cvout[(e & 3) * 64 + (e >> 2)] = s;
  }
  __syncthreads();

  const int lane = t & 63;
  const int wid = t >> 6;
  {
    int p = wid;
    float val = cvout[p * 64 + lane];
    float ssum = val;
#pragma unroll
    for (int off = 1; off < 64; off <<= 1) ssum += __shfl_xor(ssum, off);
    float mean = ssum * (1.f / 64.f);
    float dv = val - mean;
    float sq = dv * dv;
#pragma unroll
    for (int off = 1; off < 64; off <<= 1) sq += __shfl_xor(sq, off);
    float rs = 1.0f / sqrtf(sq * (1.f / 64.f) + 1e-5f);
    xnl[p * 64 + lane] = dv * rs * gamma[lane] + beta[lane];
  }
  __syncthreads();

  // KV projection: pgk = t>>7 (2 patches each), j = t&127
  const int pgk = t >> 7;
  const int j = t & 127;
  float a2[2] = {0.f, 0.f};
  for (int c = 0; c < 64; ++c) {
    float w = wkvT[c * 128 + j];
#pragma unroll
    for (int q = 0; q < 2; ++q)
      a2[q] = fmaf(xnl[(pgk * 2 + q) * 64 + c], w, a2[q]);
  }
  float bj = bkv[j];
#pragma unroll
  for (int q = 0; q < 2; ++q) {
    int p = pgk * 2 + q;
    int pid = pg * 4 + p;  // key index
    float val = a2[q] + bj;
    unsigned short h, l;
    split1(val, h, l);
    if (j < 64) {
      // K A-frag: row=key, k=ic
      int tr = pid >> 5, ks = j >> 4, e8 = j & 7;
      int ln = (pid & 31) | (((j >> 3) & 1) << 5);
      size_t base = OFF_KF + (size_t)(b * 2) * 32768 +
                    (size_t)((tr * 4 + ks) * 64 + ln) * 16 + e8 * 2;
      *(unsigned short*)(wsb + base) = h;
      *(unsigned short*)(wsb + base + 32768) = l;
    } else {
      // V^T A-frag: row=d, k=key
      int d = j - 64;
      int td = d >> 5, ks = pid >> 4, e8 = pid & 7;
      int ln = (d & 31) | (((pid >> 3) & 1) << 5);
      size_t base = OFF_VF + (size_t)(b * 2) * 32768 +
                    (size_t)((td * 16 + ks) * 64 + ln) * 16 + e8 * 2;
      *(unsigned short*)(wsb + base) = h;
      *(unsigned short*)(wsb + base + 32768) = l;
    }
  }
}

// ---- k2: per-wave flash attention, no LDS, no barriers ---------------------
// grid: 1024 blocks * 256 threads = 4096 waves; wave owns 32 queries.
// batch = bid&7 pins each batch's K/V frags (128KB) to one XCD's L2.
__global__ __launch_bounds__(256) void k2_attn(
    const float* __restrict__ x, const float* __restrict__ bq,
    const float* __restrict__ bproj, const char* __restrict__ wsb,
    float* __restrict__ out) {
  const int b  = blockIdx.x & 7;
  const int tb = blockIdx.x >> 3;  // 0..127
  const int t = threadIdx.x;
  const int w = t >> 6;
  const int lane = t & 63;
  const int l31 = lane & 31;
  const int lh = lane >> 5;
  const int n0 = tb * 128 + w * 32;
  const int q = n0 + l31;  // this lane's query (as MFMA col)

  const char* kf_b = wsb + OFF_KF + (size_t)(b * 2) * 32768;
  const char* vt_b = wsb + OFF_VF + (size_t)(b * 2) * 32768;

  // ---- qproj: Cq = Wq @ X^T  (rows=out-channel, cols=queries) ----
  bhalf8 QBh[4], QBl[4];  // Q^T B-frags, k-slice = channel slice
  {
    bhalf8 WAh[2][4], WAl[2][4];
#pragma unroll
    for (int t2 = 0; t2 < 2; ++t2)
#pragma unroll
      for (int ks = 0; ks < 4; ++ks) {
        const char* p = wsb + OFF_WQF + (size_t)((t2 * 4 + ks) * 64 + lane) * 16;
        WAh[t2][ks] = *(const bhalf8*)p;
        WAl[t2][ks] = *(const bhalf8*)(p + 8192);
      }
    const float* xrow = x + ((size_t)b * kN + q) * 64 + lh * 8;
    f32x16 cq[2];
#pragma unroll
    for (int t2 = 0; t2 < 2; ++t2)
#pragma unroll
      for (int r = 0; r < 16; ++r) cq[t2][r] = 0.f;
    __builtin_amdgcn_s_setprio(1);
#pragma unroll
    for (int ks = 0; ks < 4; ++ks) {
      U8F u;
      u.q.a = *(const float4*)(xrow + ks * 16);
      u.q.b = *(const float4*)(xrow + ks * 16 + 4);
      bhalf8 bh, bl;
      split8(u.f, bh, bl);
#pragma unroll
      for (int t2 = 0; t2 < 2; ++t2) {
        cq[t2] = MFMA32(WAh[t2][ks], bh, cq[t2]);
        cq[t2] = MFMA32(WAh[t2][ks], bl, cq[t2]);
        cq[t2] = MFMA32(WAl[t2][ks], bh, cq[t2]);
      }
    }
    __builtin_amdgcn_s_setprio(0);
    // bias (+bq) * 0.125, pack, build Q^T frags
    unsigned HQ[2][8], LQ[2][8];
#pragma unroll
    for (int t2 = 0; t2 < 2; ++t2)
#pragma unroll
      for (int rq = 0; rq < 4; ++rq) {
        U4F b4;
        b4.v = *(const float4*)(bq + t2 * 32 + rq * 8 + lh * 4);
        float v0 = (cq[t2][rq * 4 + 0] + b4.f[0]) * 0.125f;
        float v1 = (cq[t2][rq * 4 + 1] + b4.f[1]) * 0.125f;
        float v2 = (cq[t2][rq * 4 + 2] + b4.f[2]) * 0.125f;
        float v3 = (cq[t2][rq * 4 + 3] + b4.f[3]) * 0.125f;
        HQ[t2][rq * 2 + 0] = pack2(v0, v1, LQ[t2][rq * 2 + 0]);
        HQ[t2][rq * 2 + 1] = pack2(v2, v3, LQ[t2][rq * 2 + 1]);
      }
#pragma unroll
    for (int t2 = 0; t2 < 2; ++t2)
#pragma unroll
      for (int s = 0; s < 2; ++s) {
        QBh[t2 * 2 + s] = asm_frag(&HQ[t2][s * 4], lh);
        QBl[t2 * 2 + s] = asm_frag(&LQ[t2][s * 4], lh);
      }
  }

  // ---- flash loop over 8 key tiles (32 keys each) ----
  f32x16 accO[2];  // O^T: rows = d (2 tiles), cols = queries (lane)
#pragma unroll
  for (int td = 0; td < 2; ++td)
#pragma unroll
    for (int r = 0; r < 16; ++r) accO[td][r] = 0.f;
  float m = -1e30f, l = 0.f;

#pragma unroll 2
  for (int kt = 0; kt < 8; ++kt) {
    // K A-frags (row=key, k=channel)
    bhalf8 KAh[4], KAl[4];
#pragma unroll
    for (int ks = 0; ks < 4; ++ks) {
      const char* p = kf_b + (size_t)((kt * 4 + ks) * 64 + lane) * 16;
      KAh[ks] = *(const bhalf8*)p;
      KAl[ks] = *(const bhalf8*)(p + 32768);
    }
    // V^T A-frags (row=d, k=key) for this key tile
    bhalf8 VAh[2][2], VAl[2][2];
#pragma unroll
    for (int td = 0; td < 2; ++td)
#pragma unroll
      for (int s = 0; s < 2; ++s) {
        const char* p =
            vt_b + (size_t)((td * 16 + kt * 2 + s) * 64 + lane) * 16;
        VAh[td][s] = *(const bhalf8*)p;
        VAl[td][s] = *(const bhalf8*)(p + 32768);
      }

    // S^T tile = K @ Q^T (rows=keys, cols=queries)
    f32x16 s16;
#pragma unroll
    for (int r = 0; r < 16; ++r) s16[r] = 0.f;
    __builtin_amdgcn_s_setprio(1);
#pragma unroll
    for (int ks = 0; ks < 4; ++ks) {
      s16 = MFMA32(KAh[ks], QBh[ks], s16);
      s16 = MFMA32(KAh[ks], QBl[ks], s16);
      s16 = MFMA32(KAl[ks], QBh[ks], s16);
    }
    __builtin_amdgcn_s_setprio(0);

    // online softmax (per-query stats live in lane = col)
    float mt = s16[0];
#pragma unroll
    for (int r = 1; r < 16; ++r) mt = fmaxf(mt, s16[r]);
    mt = fmaxf(mt, __shfl_xor(mt, 32));
    if (!__all(mt <= m + 8.0f)) {  // defer-max (T13)
      float mn = fmaxf(m, mt);
      float f = __expf(m - mn);
      l *= f;
#pragma unroll
      for (int td = 0; td < 2; ++td)
#pragma unroll
        for (int r = 0; r < 16; ++r) accO[td][r] *= f;
      m = mn;
    }
    float ps = 0.f;
    unsigned HP[8], LP[8];
#pragma unroll
    for (int pr = 0; pr < 8; ++pr) {
      float p0 = __expf(s16[2 * pr] - m);
      float p1 = __expf(s16[2 * pr + 1] - m);
      ps += p0 + p1;
      HP[pr] = pack2(p0, p1, LP[pr]);
    }
    ps += __shfl_xor(ps, 32);
    l += ps;

    bhalf8 PBh[2], PBl[2];
#pragma unroll
    for (int s = 0; s < 2; ++s) {
      PBh[s] = asm_frag(&HP[s * 4], lh);
      PBl[s] = asm_frag(&LP[s * 4], lh);
    }
    __builtin_amdgcn_s_setprio(1);
#pragma unroll
    for (int td = 0; td < 2; ++td)
#pragma unroll
      for (int s = 0; s < 2; ++s) {
        accO[td] = MFMA32(VAh[td][s], PBh[s], accO[td]);
        accO[td] = MFMA32(VAh[td][s], PBl[s], accO[td]);
        accO[td] = MFMA32(VAl[td][s], PBh[s], accO[td]);
      }
    __builtin_amdgcn_s_setprio(0);
  }

  // ---- normalize, build O^T frags ----
  const float inv = 1.0f / l;
  unsigned HO[2][8], LO[2][8];
#pragma unroll
  for (int td = 0; td < 2; ++td)
#pragma unroll
    for (int pr = 0; pr < 8; ++pr)
      HO[td][pr] = pack2(accO[td][2 * pr] * inv, accO[td][2 * pr + 1] * inv,
                         LO[td][pr]);
  bhalf8 OBh[4], OBl[4];
#pragma unroll
  for (int td = 0; td < 2; ++td)
#pragma unroll
    for (int s = 0; s < 2; ++s) {
      OBh[td * 2 + s] = asm_frag(&HO[td][s * 4], lh);
      OBl[td * 2 + s] = asm_frag(&LO[td][s * 4], lh);
    }

  // ---- out-proj: out^T = Wp @ O^T ----
  bhalf8 PAh[2][4], PAl[2][4];
#pragma unroll
  for (int to = 0; to < 2; ++to)
#pragma unroll
    for (int ks = 0; ks < 4; ++ks) {
      const char* p = wsb + OFF_WPF + (size_t)((to * 4 + ks) * 64 + lane) * 16;
      PAh[to][ks] = *(const bhalf8*)p;
      PAl[to][ks] = *(const bhalf8*)(p + 8192);
    }
  f32x16 co[2];
#pragma unroll
  for (int to = 0; to < 2; ++to)
#pragma unroll
    for (int r = 0; r < 16; ++r) co[to][r] = 0.f;
  __builtin_amdgcn_s_setprio(1);
#pragma unroll
  for (int ks = 0; ks < 4; ++ks)
#pragma unroll
    for (int to = 0; to < 2; ++to) {
      co[to] = MFMA32(PAh[to][ks], OBh[ks], co[to]);
      co[to] = MFMA32(PAh[to][ks], OBl[ks], co[to]);
      co[to] = MFMA32(PAl[to][ks], OBh[ks], co[to]);
    }
  __builtin_amdgcn_s_setprio(0);

  // ---- bias + store (row=out-channel in regs, col=query=lane) ----
  float* ob = out + ((size_t)b * kN + q) * 64;
#pragma unroll
  for (int to = 0; to < 2; ++to)
#pragma unroll
    for (int rq = 0; rq < 4; ++rq) {
      U4F b4;
      b4.v = *(const float4*)(bproj + to * 32 + rq * 8 + lh * 4);
      float4 st = make_float4(co[to][rq * 4 + 0] + b4.f[0],
                              co[to][rq * 4 + 1] + b4.f[1],
                              co[to][rq * 4 + 2] + b4.f[2],
                              co[to][rq * 4 + 3] + b4.f[3]);
      *(float4*)(ob + to * 32 + rq * 8 + lh * 4) = st;
    }
}

}  // namespace

extern "C" void kernel_launch(void* const* d_in, const int* in_sizes, int n_in,
                              void* d_out, int out_size, void* d_ws, size_t ws_size,
                              hipStream_t stream) {
  (void)in_sizes; (void)n_in; (void)out_size; (void)ws_size;
  const float* x     = (const float*)d_in[0];
  const float* wq    = (const float*)d_in[1];
  const float* bq    = (const float*)d_in[2];
  const float* wkv   = (const float*)d_in[3];
  const float* bkv   = (const float*)d_in[4];
  const float* wproj = (const float*)d_in[5];
  const float* bproj = (const float*)d_in[6];
  const float* wsr   = (const float*)d_in[7];
  const float* gamma = (const float*)d_in[8];
  const float* beta  = (const float*)d_in[9];
  float* out = (float*)d_out;
  char* wsb  = (char*)d_ws;

  k0_reorder<<<1088, 256, 0, stream>>>(wq, wkv, wproj, wsr, wsb);
  k1_conv_ln_kv<<<512, 256, 0, stream>>>(x, bkv, gamma, beta, wsb);
  k2_attn<<<1024, 256, 0, stream>>>(x, bq, bproj, wsb, out);
}

// Round 6
// 100.362 us; speedup vs baseline: 1.0453x; 1.0152x over previous
//
#include <hip/hip_runtime.h>
#include <hip/hip_bf16.h>

// EfficientSelfAttn (PVT spatial-reduction attention), fp32 in/out.
// B=8, N=16384, C=64, NH=1, SR=8, H=W=128 -> Nk=256.
//
// R6: k2 = per-wave flash attention with ZERO cross-lane fragment assembly.
// Key idea: contraction-index layouts (K channels, V keys, Wp k) are stored
// sigma-permuted so each lane's 32x32 C-layout registers ARE the next MFMA's
// A/B fragment slots: slot(n): rho=(n&3)|((n>>3)<<2), hb=(n>>2)&1.
// Forward: slot(ks,hb,e8) holds natural index 16ks+(e8&3)+8*(e8>>2)+4*hb.
// Attention is permutation-invariant over keys (K,V share order); GEMMs over
// their contraction index (both operands share order). Scalar cross-half
// reduction uses proven __shfl_xor(,32). exp2-domain softmax, tree reduce,
// split QK chains.

namespace {

constexpr int kN = 16384;

// ---- ws byte layout ----
constexpr size_t OFF_WSRT = 0;              // f32 [r=kh*8+kw][ic][oc] 64*64*64
constexpr size_t OFF_WKVT = 1048576;        // f32 [c][j] 64*128
constexpr size_t OFF_WQF  = 1081344;        // bf16 A-frag [pl2][t2][ks4][64][8] (natural k)
constexpr size_t OFF_WPF  = 1097728;        // bf16 A-frag [pl2][t2][ks4][64][8] (sigma k)
constexpr size_t OFF_KF   = 1114112;        // bf16 A-frag [b][pl2][tr8][ks4][64][8] (sigma ch)
constexpr size_t OFF_VF   = 1638400;        // bf16 A-frag V^T [b][pl2][td2][ks16][64][8] (sigma key)

typedef __attribute__((ext_vector_type(8))) __bf16 bhalf8;
typedef __attribute__((ext_vector_type(16))) float f32x16;

#define MFMA32(a, b, c) __builtin_amdgcn_mfma_f32_32x32x16_bf16((a), (b), (c), 0, 0, 0)

__device__ __forceinline__ void split1(float x, unsigned short& h, unsigned short& l) {
  unsigned u = __float_as_uint(x);
  h = (unsigned short)(u >> 16);
  float r = x - __uint_as_float(u & 0xFFFF0000u);
  l = (unsigned short)(__float_as_uint(r) >> 16);
}

// pack two f32 into one dword of bf16-hi parts; lo parts via out param
__device__ __forceinline__ unsigned pack2(float a, float b, unsigned& lo) {
  unsigned ua = __float_as_uint(a), ub = __float_as_uint(b);
  unsigned hi = (ua >> 16) | (ub & 0xFFFF0000u);
  float ra = a - __uint_as_float(ua & 0xFFFF0000u);
  float rb = b - __uint_as_float(ub & 0xFFFF0000u);
  lo = (__float_as_uint(ra) >> 16) | (__float_as_uint(rb) & 0xFFFF0000u);
  return hi;
}

union U4 { unsigned u[4]; bhalf8 v; };
union U4F { float4 v; float f[4]; };
union U8F { float f[8]; struct { float4 a, b; } q; };

__device__ __forceinline__ void split8(const float* xs, bhalf8& h8, bhalf8& l8) {
  U4 H, L;
#pragma unroll
  for (int p = 0; p < 4; ++p) H.u[p] = pack2(xs[2 * p], xs[2 * p + 1], L.u[p]);
  h8 = H.v;
  l8 = L.v;
}

// ---- k0: weight reorder + fragment/split generation ------------------------
__global__ __launch_bounds__(256) void k0_reorder(
    const float* __restrict__ wq, const float* __restrict__ wkv,
    const float* __restrict__ wproj, const float* __restrict__ wsr,
    char* __restrict__ wsb) {
  int e = blockIdx.x * 256 + threadIdx.x;
  if (e < 262144) {
    int oc = e & 63, ic = (e >> 6) & 63, r = e >> 12;
    ((float*)(wsb + OFF_WSRT))[e] = wsr[oc * 4096 + ic * 64 + r];
  } else if (e < 270336) {
    int i = e - 262144;
    int j = i & 127, c = i >> 7;
    ((float*)(wsb + OFF_WKVT))[i] = wkv[j * 64 + c];
  } else if (e < 278528) {
    int i = e - 270336;
    bool iswp = i >= 4096;
    int ii = i & 4095;
    int e8 = ii & 7, ln = (ii >> 3) & 63, ks = (ii >> 9) & 3, t2 = ii >> 11;
    int c = t2 * 32 + (ln & 31);
    int hb = ln >> 5;
    // Wq: natural k (pairs with natural X frags). Wp: sigma k (pairs with
    // O^T C-layout regs used directly as B-frags).
    int kk = iswp ? (ks * 16 + (e8 & 3) + 8 * (e8 >> 2) + 4 * hb)
                  : (ks * 16 + hb * 8 + e8);
    const float* src = iswp ? wproj : wq;
    float v = src[c * 64 + kk];
    unsigned short h, l;
    split1(v, h, l);
    size_t base = (iswp ? OFF_WPF : OFF_WQF) + (size_t)ii * 2;
    *(unsigned short*)(wsb + base) = h;
    *(unsigned short*)(wsb + base + 8192) = l;
  }
}

// ---- k1: conv + LN + KV, emits K and V^T hi+lo A-fragments (sigma slots) ---
// grid: 512 = 8 batches * 64 patch-groups (4 patches each). 256 threads.
__global__ __launch_bounds__(256) void k1_conv_ln_kv(
    const float* __restrict__ x, const float* __restrict__ bkv,
    const float* __restrict__ gamma, const float* __restrict__ beta,
    char* __restrict__ wsb) {
  const float* __restrict__ wsrT = (const float*)(wsb + OFF_WSRT);
  const float* __restrict__ wkvT = (const float*)(wsb + OFF_WKVT);

  const int b  = blockIdx.x >> 6;
  const int pg = blockIdx.x & 63;
  const int t  = threadIdx.x;
  const int ocp = t & 31;
  const int icg = t >> 5;

  __shared__ float chunk[2048];
  __shared__ float red[2048];
  __shared__ float cvout[256];
  __shared__ float xnl[256];

  const float* __restrict__ xb = x + (size_t)b * (kN * 64);

  float acc0[4], acc1[4];
#pragma unroll
  for (int p = 0; p < 4; ++p) { acc0[p] = 0.f; acc1[p] = 0.f; }

  for (int kh = 0; kh < 8; ++kh) {
    __syncthreads();
#pragma unroll
    for (int it = 0; it < 2; ++it) {
      int f = it * 1024 + t * 4;
      int p = f >> 9;
      int w512 = f & 511;
      int pid = pg * 4 + p;
      int oh = pid >> 4, ow = pid & 15;
      const float* src = xb + oh * 65536 + ow * 512 + kh * 8192 + w512;
      *(float4*)&chunk[f] = *(const float4*)src;
    }
    __syncthreads();
    for (int kw = 0; kw < 8; ++kw) {
      const int rbase = ((kh * 8 + kw) * 64 + icg * 8) * 64;
      float w0[8], w1[8];
#pragma unroll
      for (int ii = 0; ii < 8; ++ii) {
        w0[ii] = wsrT[rbase + ii * 64 + ocp];
        w1[ii] = wsrT[rbase + ii * 64 + ocp + 32];
      }
#pragma unroll
      for (int p = 0; p < 4; ++p) {
        const float* cp = &chunk[p * 512 + kw * 64 + icg * 8];
        float4 a = *(const float4*)cp;
        float4 bb = *(const float4*)(cp + 4);
        float xs[8] = {a.x, a.y, a.z, a.w, bb.x, bb.y, bb.z, bb.w};
#pragma unroll
        for (int ii = 0; ii < 8; ++ii) {
          acc0[p] = fmaf(w0[ii], xs[ii], acc0[p]);
          acc1[p] = fmaf(w1[ii], xs[ii], acc1[p]);
        }
      }
    }
  }

#pragma unroll
  for (int p = 0; p < 4; ++p) {
    red[icg * 256 + ocp * 4 + p] = acc0[p];
    red[icg * 256 + (ocp + 32) * 4 + p] = acc1[p];
  }
  __syncthreads();
  {
    int e = t;  // e = oc*4 + p
    float s = 0.f;
#pragma unroll
    for (int g = 0; g < 8; ++g) s += red[g * 256 + e];
    cvout[(e & 3) * 64 + (e >> 2)] = s;
  }
  __syncthreads();

  const int lane = t & 63;
  const int wid = t >> 6;
  {
    int p = wid;
    float val = cvout[p * 64 + lane];
    float ssum = val;
#pragma unroll
    for (int off = 1; off < 64; off <<= 1) ssum += __shfl_xor(ssum, off);
    float mean = ssum * (1.f / 64.f);
    float dv = val - mean;
    float sq = dv * dv;
#pragma unroll
    for (int off = 1; off < 64; off <<= 1) sq += __shfl_xor(sq, off);
    float rs = 1.0f / sqrtf(sq * (1.f / 64.f) + 1e-5f);
    xnl[p * 64 + lane] = dv * rs * gamma[lane] + beta[lane];
  }
  __syncthreads();

  // KV projection: pgk = t>>7 (2 patches each), j = t&127
  const int pgk = t >> 7;
  const int j = t & 127;
  float a2[2] = {0.f, 0.f};
  for (int c = 0; c < 64; ++c) {
    float w = wkvT[c * 128 + j];
#pragma unroll
    for (int q = 0; q < 2; ++q)
      a2[q] = fmaf(xnl[(pgk * 2 + q) * 64 + c], w, a2[q]);
  }
  float bj = bkv[j];
#pragma unroll
  for (int q = 0; q < 2; ++q) {
    int p = pgk * 2 + q;
    int pid = pg * 4 + p;  // key index
    float val = a2[q] + bj;
    unsigned short h, l;
    split1(val, h, l);
    if (j < 64) {
      // K A-frag: row = key (natural), k-slot = sigma(channel j)
      int n = j & 15, ks = j >> 4;
      int rho = (n & 3) | (((n >> 3) & 1) << 2);
      int hb = (n >> 2) & 1;
      int tr = pid >> 5;
      int ln = (pid & 31) | (hb << 5);
      size_t base = OFF_KF + (size_t)(b * 2) * 32768 +
                    (size_t)((tr * 4 + ks) * 64 + ln) * 16 + rho * 2;
      *(unsigned short*)(wsb + base) = h;
      *(unsigned short*)(wsb + base + 32768) = l;
    } else {
      // V^T A-frag: row = d (natural), k-slot = sigma(key pid)
      int d = j - 64;
      int n = pid & 15, ks = pid >> 4;
      int rho = (n & 3) | (((n >> 3) & 1) << 2);
      int hb = (n >> 2) & 1;
      int td = d >> 5;
      int ln = (d & 31) | (hb << 5);
      size_t base = OFF_VF + (size_t)(b * 2) * 32768 +
                    (size_t)((td * 16 + ks) * 64 + ln) * 16 + rho * 2;
      *(unsigned short*)(wsb + base) = h;
      *(unsigned short*)(wsb + base + 32768) = l;
    }
  }
}

// ---- k2: per-wave flash attention, no LDS, no barriers, no lane exchange ---
// grid: 1024 blocks * 256 threads = 4096 waves; wave owns 32 queries.
__global__ __launch_bounds__(256) void k2_attn(
    const float* __restrict__ x, const float* __restrict__ bq,
    const float* __restrict__ bproj, const char* __restrict__ wsb,
    float* __restrict__ out) {
  const int b  = blockIdx.x & 7;
  const int tb = blockIdx.x >> 3;  // 0..127
  const int t = threadIdx.x;
  const int w = t >> 6;
  const int lane = t & 63;
  const int l31 = lane & 31;
  const int lh = lane >> 5;
  const int n0 = tb * 128 + w * 32;
  const int q = n0 + l31;  // this lane's query (as MFMA col)

  const char* kf_b = wsb + OFF_KF + (size_t)(b * 2) * 32768;
  const char* vt_b = wsb + OFF_VF + (size_t)(b * 2) * 32768;

  // softmax in exp2 domain: fold 0.125*log2e into q-scale
  const float SCALE = 0.125f * 1.44269504088896f;

  // ---- qproj: Cq = Wq @ X^T  (rows=out-channel, cols=queries) ----
  bhalf8 QBh[4], QBl[4];  // Q^T B-frags (C-regs reinterpreted; sigma slots)
  {
    bhalf8 WAh[2][4], WAl[2][4];
#pragma unroll
    for (int t2 = 0; t2 < 2; ++t2)
#pragma unroll
      for (int ks = 0; ks < 4; ++ks) {
        const char* p = wsb + OFF_WQF + (size_t)((t2 * 4 + ks) * 64 + lane) * 16;
        WAh[t2][ks] = *(const bhalf8*)p;
        WAl[t2][ks] = *(const bhalf8*)(p + 8192);
      }
    const float* xrow = x + ((size_t)b * kN + q) * 64 + lh * 8;
    f32x16 cq[2];
#pragma unroll
    for (int t2 = 0; t2 < 2; ++t2)
#pragma unroll
      for (int r = 0; r < 16; ++r) cq[t2][r] = 0.f;
    __builtin_amdgcn_s_setprio(1);
#pragma unroll
    for (int ks = 0; ks < 4; ++ks) {
      U8F u;
      u.q.a = *(const float4*)(xrow + ks * 16);
      u.q.b = *(const float4*)(xrow + ks * 16 + 4);
      bhalf8 bh, bl;
      split8(u.f, bh, bl);
#pragma unroll
      for (int t2 = 0; t2 < 2; ++t2) {
        cq[t2] = MFMA32(WAh[t2][ks], bh, cq[t2]);
        cq[t2] = MFMA32(WAh[t2][ks], bl, cq[t2]);
        cq[t2] = MFMA32(WAl[t2][ks], bh, cq[t2]);
      }
    }
    __builtin_amdgcn_s_setprio(0);
    // bias + scale, pack; C-regs (2pr,2pr+1) become frag dwords directly
    U4 QH[2][2], QL[2][2];  // [t2][sl]
#pragma unroll
    for (int t2 = 0; t2 < 2; ++t2)
#pragma unroll
      for (int rq = 0; rq < 4; ++rq) {
        U4F b4;
        b4.v = *(const float4*)(bq + t2 * 32 + rq * 8 + lh * 4);
        float v0 = (cq[t2][rq * 4 + 0] + b4.f[0]) * SCALE;
        float v1 = (cq[t2][rq * 4 + 1] + b4.f[1]) * SCALE;
        float v2 = (cq[t2][rq * 4 + 2] + b4.f[2]) * SCALE;
        float v3 = (cq[t2][rq * 4 + 3] + b4.f[3]) * SCALE;
        unsigned lo;
        QH[t2][rq >> 1].u[(rq & 1) * 2 + 0] = pack2(v0, v1, lo);
        QL[t2][rq >> 1].u[(rq & 1) * 2 + 0] = lo;
        QH[t2][rq >> 1].u[(rq & 1) * 2 + 1] = pack2(v2, v3, lo);
        QL[t2][rq >> 1].u[(rq & 1) * 2 + 1] = lo;
      }
#pragma unroll
    for (int t2 = 0; t2 < 2; ++t2)
#pragma unroll
      for (int sl = 0; sl < 2; ++sl) {
        QBh[t2 * 2 + sl] = QH[t2][sl].v;
        QBl[t2 * 2 + sl] = QL[t2][sl].v;
      }
  }

  // ---- flash loop over 8 key tiles (32 keys each) ----
  f32x16 accO[2];  // O^T: rows = d (2 tiles), cols = queries (lane)
#pragma unroll
  for (int td = 0; td < 2; ++td)
#pragma unroll
    for (int r = 0; r < 16; ++r) accO[td][r] = 0.f;
  float m = -1e30f, l = 0.f;

#pragma unroll 2
  for (int kt = 0; kt < 8; ++kt) {
    // K A-frags (row=key, k-slot=sigma(channel))
    bhalf8 KAh[4], KAl[4];
#pragma unroll
    for (int ks = 0; ks < 4; ++ks) {
      const char* p = kf_b + (size_t)((kt * 4 + ks) * 64 + lane) * 16;
      KAh[ks] = *(const bhalf8*)p;
      KAl[ks] = *(const bhalf8*)(p + 32768);
    }

    // S^T tile = K @ Q^T, two independent 6-MFMA chains
    f32x16 sa, sb;
#pragma unroll
    for (int r = 0; r < 16; ++r) { sa[r] = 0.f; sb[r] = 0.f; }
    __builtin_amdgcn_s_setprio(1);
#pragma unroll
    for (int ks = 0; ks < 2; ++ks) {
      sa = MFMA32(KAh[ks], QBh[ks], sa);
      sa = MFMA32(KAh[ks], QBl[ks], sa);
      sa = MFMA32(KAl[ks], QBh[ks], sa);
    }
#pragma unroll
    for (int ks = 2; ks < 4; ++ks) {
      sb = MFMA32(KAh[ks], QBh[ks], sb);
      sb = MFMA32(KAh[ks], QBl[ks], sb);
      sb = MFMA32(KAl[ks], QBh[ks], sb);
    }
    __builtin_amdgcn_s_setprio(0);

    // V^T A-frags (row=d, k-slot=sigma(key)) — latency hides under softmax
    bhalf8 VAh[2][2], VAl[2][2];
#pragma unroll
    for (int td = 0; td < 2; ++td)
#pragma unroll
      for (int s = 0; s < 2; ++s) {
        const char* p =
            vt_b + (size_t)((td * 16 + kt * 2 + s) * 64 + lane) * 16;
        VAh[td][s] = *(const bhalf8*)p;
        VAl[td][s] = *(const bhalf8*)(p + 32768);
      }

    f32x16 s16 = sa + sb;

    // online softmax in exp2 domain; tree max; shfl only for cross-half
    float m8[8];
#pragma unroll
    for (int i = 0; i < 8; ++i) m8[i] = fmaxf(s16[2 * i], s16[2 * i + 1]);
    float m4a = fmaxf(m8[0], m8[1]), m4b = fmaxf(m8[2], m8[3]);
    float m4c = fmaxf(m8[4], m8[5]), m4d = fmaxf(m8[6], m8[7]);
    float mt = fmaxf(fmaxf(m4a, m4b), fmaxf(m4c, m4d));
    mt = fmaxf(mt, __shfl_xor(mt, 32));
    if (!__all(mt <= m + 11.5f)) {  // defer-max (T13), log2 units
      float mn = fmaxf(m, mt);
      float f = exp2f(m - mn);
      l *= f;
#pragma unroll
      for (int td = 0; td < 2; ++td)
#pragma unroll
        for (int r = 0; r < 16; ++r) accO[td][r] *= f;
      m = mn;
    }
    U4 PH[2], PL[2];
    float sp[4] = {0.f, 0.f, 0.f, 0.f};
#pragma unroll
    for (int pr = 0; pr < 8; ++pr) {
      float p0 = exp2f(s16[2 * pr] - m);
      float p1 = exp2f(s16[2 * pr + 1] - m);
      sp[pr & 3] += p0 + p1;
      unsigned lo;
      PH[pr >> 2].u[pr & 3] = pack2(p0, p1, lo);
      PL[pr >> 2].u[pr & 3] = lo;
    }
    float ps = (sp[0] + sp[1]) + (sp[2] + sp[3]);
    ps += __shfl_xor(ps, 32);
    l += ps;

    __builtin_amdgcn_s_setprio(1);
#pragma unroll
    for (int td = 0; td < 2; ++td)
#pragma unroll
      for (int s = 0; s < 2; ++s) {
        accO[td] = MFMA32(VAh[td][s], PH[s].v, accO[td]);
        accO[td] = MFMA32(VAh[td][s], PL[s].v, accO[td]);
        accO[td] = MFMA32(VAl[td][s], PH[s].v, accO[td]);
      }
    __builtin_amdgcn_s_setprio(0);
  }

  // ---- normalize, O^T C-regs become B-frags directly ----
  const float inv = 1.0f / l;
  U4 OH[2][2], OL[2][2];  // [td][sl]
#pragma unroll
  for (int td = 0; td < 2; ++td)
#pragma unroll
    for (int pr = 0; pr < 8; ++pr) {
      unsigned lo;
      OH[td][pr >> 2].u[pr & 3] =
          pack2(accO[td][2 * pr] * inv, accO[td][2 * pr + 1] * inv, lo);
      OL[td][pr >> 2].u[pr & 3] = lo;
    }
  bhalf8 OBh[4], OBl[4];
#pragma unroll
  for (int td = 0; td < 2; ++td)
#pragma unroll
    for (int sl = 0; sl < 2; ++sl) {
      OBh[td * 2 + sl] = OH[td][sl].v;
      OBl[td * 2 + sl] = OL[td][sl].v;
    }

  // ---- out-proj: out^T = Wp @ O^T (Wp k-slots are sigma) ----
  bhalf8 PAh[2][4], PAl[2][4];
#pragma unroll
  for (int to = 0; to < 2; ++to)
#pragma unroll
    for (int ks = 0; ks < 4; ++ks) {
      const char* p = wsb + OFF_WPF + (size_t)((to * 4 + ks) * 64 + lane) * 16;
      PAh[to][ks] = *(const bhalf8*)p;
      PAl[to][ks] = *(const bhalf8*)(p + 8192);
    }
  f32x16 co[2];
#pragma unroll
  for (int to = 0; to < 2; ++to)
#pragma unroll
    for (int r = 0; r < 16; ++r) co[to][r] = 0.f;
  __builtin_amdgcn_s_setprio(1);
#pragma unroll
  for (int ks = 0; ks < 4; ++ks)
#pragma unroll
    for (int to = 0; to < 2; ++to) {
      co[to] = MFMA32(PAh[to][ks], OBh[ks], co[to]);
      co[to] = MFMA32(PAh[to][ks], OBl[ks], co[to]);
      co[to] = MFMA32(PAl[to][ks], OBh[ks], co[to]);
    }
  __builtin_amdgcn_s_setprio(0);

  // ---- bias + store (row=out-channel in regs, col=query=lane) ----
  float* ob = out + ((size_t)b * kN + q) * 64;
#pragma unroll
  for (int to = 0; to < 2; ++to)
#pragma unroll
    for (int rq = 0; rq < 4; ++rq) {
      U4F b4;
      b4.v = *(const float4*)(bproj + to * 32 + rq * 8 + lh * 4);
      float4 st = make_float4(co[to][rq * 4 + 0] + b4.f[0],
                              co[to][rq * 4 + 1] + b4.f[1],
                              co[to][rq * 4 + 2] + b4.f[2],
                              co[to][rq * 4 + 3] + b4.f[3]);
      *(float4*)(ob + to * 32 + rq * 8 + lh * 4) = st;
    }
}

}  // namespace

extern "C" void kernel_launch(void* const* d_in, const int* in_sizes, int n_in,
                              void* d_out, int out_size, void* d_ws, size_t ws_size,
                              hipStream_t stream) {
  (void)in_sizes; (void)n_in; (void)out_size; (void)ws_size;
  const float* x     = (const float*)d_in[0];
  const float* wq    = (const float*)d_in[1];
  const float* bq    = (const float*)d_in[2];
  const float* wkv   = (const float*)d_in[3];
  const float* bkv   = (const float*)d_in[4];
  const float* wproj = (const float*)d_in[5];
  const float* bproj = (const float*)d_in[6];
  const float* wsr   = (const float*)d_in[7];
  const float* gamma = (const float*)d_in[8];
  const float* beta  = (const float*)d_in[9];
  float* out = (float*)d_out;
  char* wsb  = (char*)d_ws;

  k0_reorder<<<1088, 256, 0, stream>>>(wq, wkv, wproj, wsr, wsb);
  k1_conv_ln_kv<<<512, 256, 0, stream>>>(x, bkv, gamma, beta, wsb);
  k2_attn<<<1024, 256, 0, stream>>>(x, bq, bproj, wsb, out);
}